// Round 2
// baseline (176.374 us; speedup 1.0000x reference)
//
#include <hip/hip_runtime.h>
#include <math.h>

// GAT aggregation: B=8,S=512,N=32,H=256,V=100001  (npos = 4096)
// Round-12 = Round-11 + one-line correctness fix.
// R11 bug: __builtin_amdgcn_readlane(pr, c) with FLOAT pr — the builtin is
// int(int,int), so pr was implicitly TRUNCATED to int (0 for pr<1, 1 for the
// max lane) => output collapsed to the argmax row. Fix: bit-cast via
// __float_as_int / __int_as_float around the lane broadcast.
//
// Structure (unchanged from R11):
//   z(src,cand) = emb[src]·a_w[0:H] + emb[cand]·a_w[H:2H] + b
//               = p1[src] + p2[cand] + b
// Pass 1 (proj_kernel): pv[v] = (p1[v], p2[v]) for all V rows.
// Pass 2 (agg_kernel): ONE WAVE PER POSITION. Softmax weights from 4-8 B
//   gathers of pv — decoupled from the 1 KB row gathers, which stream in
//   concurrently. No __syncthreads, no cross-wave merge, 12 DS ops total.

constexpr int   H     = 256;
constexpr int   NN    = 32;            // neighbors
constexpr int   C     = NN + 1;        // max candidates (self + neighbors)
constexpr float SLOPE = 0.2f;

// ---------------- Pass 1: per-vocab projections ----------------
constexpr int RPI = 4;                 // rows per wave-iteration

__global__ __launch_bounds__(256) void proj_kernel(
    const float* __restrict__ emb,     // [V, H]
    const float* __restrict__ a_w,     // [2H]
    float2*      __restrict__ pv,      // [V] = (p1, p2)
    int V)
{
  const int lane = threadIdx.x & 63;
  const int wid  = blockIdx.x * 4 + (threadIdx.x >> 6);
  const int nw   = gridDim.x * 4;
  const int l4   = lane << 2;

  const float4 aw1 = *(const float4*)(a_w + l4);
  const float4 aw2 = *(const float4*)(a_w + H + l4);
  const float4* __restrict__ embv = (const float4*)emb;

  for (int base = wid * RPI; base < V; base += nw * RPI) {
    float red[2 * RPI];
#pragma unroll
    for (int i = 0; i < RPI; ++i) {
      float4 r = {0.f, 0.f, 0.f, 0.f};
      if (base + i < V) r = embv[(size_t)(base + i) * (H / 4) + lane];
      red[2 * i]     = r.x * aw1.x + r.y * aw1.y + r.z * aw1.z + r.w * aw1.w;
      red[2 * i + 1] = r.x * aw2.x + r.y * aw2.y + r.z * aw2.z + r.w * aw2.w;
    }
    // one batched butterfly for all 2*RPI partial dots (independent -> pipelined)
#pragma unroll
    for (int off = 32; off > 0; off >>= 1)
#pragma unroll
      for (int t = 0; t < 2 * RPI; ++t)
        red[t] += __shfl_xor(red[t], off, 64);
    if (lane == 0) {
#pragma unroll
      for (int i = 0; i < RPI; ++i)
        if (base + i < V)
          pv[base + i] = make_float2(red[2 * i], red[2 * i + 1]);
    }
  }
}

// ---------------- Pass 2: softmax + weighted aggregate ----------------
__global__ __launch_bounds__(256) void agg_kernel(
    const int*    __restrict__ node_ids, // [npos]
    const int*    __restrict__ neighs,   // [npos, NN]
    const int*    __restrict__ mask,     // [npos, NN]
    const float*  __restrict__ emb,      // [V, H]
    const float2* __restrict__ pv,       // [V]
    const float*  __restrict__ a_b,      // [1]
    float*        __restrict__ out,      // [npos, H]
    int npos)
{
  __shared__ int sidx[4][64];            // per-wave compacted survivor ids
  const int wv   = threadIdx.x >> 6;
  const int lane = threadIdx.x & 63;
  const int pos  = blockIdx.x * 4 + wv;  // one wave per position
  if (pos >= npos) return;               // no barriers below -> safe
  const int l4 = lane << 2;

  // ---- load indices/mask, ballot-compact (per wave, no barrier) ----
  bool active = false;
  int  my     = 0;
  if (lane == 0) {
    my = node_ids[pos];
    active = true;                               // self never masked
  } else if (lane <= NN) {
    my     = neighs[pos * NN + lane - 1];
    active = (mask[pos * NN + lane - 1] == 0);   // masked -> weight +0 -> skip
  }
  const unsigned long long bal = __ballot(active);
  const int K = (int)__popcll(bal);              // wave-uniform (SGPR), K >= 1
  if (active)
    sidx[wv][(int)__popcll(bal & ((1ull << lane) - 1ull))] = my;
  // same-wave LDS write->read: DS ops are ordered within a wave
  const int cidx = sidx[wv][lane];               // lane k = survivor k's id

  const float4* __restrict__ embv = (const float4*)emb;

  // ---- issue first PF row loads NOW; their latency hides the softmax ----
  constexpr int PF = 8;
  float4 buf[PF];
#pragma unroll
  for (int j = 0; j < PF; ++j)
    if (j < K)
      buf[j] = embv[(size_t)__builtin_amdgcn_readlane(cidx, j) * (H / 4) + lane];

  // ---- scalar-path softmax: weights need only 4-8 B gathers of pv ----
  const int   iself = __builtin_amdgcn_readlane(cidx, 0);
  const float psrc  = pv[iself].x;               // uniform -> scalar load
  const float ab    = a_b[0];
  float z = -1e30f;
  if (lane < K) {
    const float zc = psrc + pv[cidx].y + ab;
    z = (zc > 0.f) ? zc : SLOPE * zc;            // LeakyReLU(0.2)
  }
  float m = z;
#pragma unroll
  for (int off = 32; off > 0; off >>= 1)
    m = fmaxf(m, __shfl_xor(m, off, 64));
  float pr = (lane < K) ? __expf(z - m) : 0.f;
  float s = pr;
#pragma unroll
  for (int off = 32; off > 0; off >>= 1)
    s += __shfl_xor(s, off, 64);
  const float inv = 1.f / s;

  // ---- weighted aggregate: stream rows, weight via readlane (SGPR) ----
  float4 acc0 = {0.f, 0.f, 0.f, 0.f};
  float4 acc1 = {0.f, 0.f, 0.f, 0.f};
#pragma unroll
  for (int c = 0; c < C; ++c) {                  // fully unrolled, static idx
    if (c < K) {                                 // scalar guard (K uniform)
      // FLOAT lane-broadcast must go through a bit-cast: the raw builtin is
      // int(int,int) and would TRUNCATE a float argument (the R11 bug).
      const float wc = __int_as_float(
          __builtin_amdgcn_readlane(__float_as_int(pr), c));
      float4 r;
      if (c < PF) r = buf[c];
      else        r = embv[(size_t)__builtin_amdgcn_readlane(cidx, c) * (H / 4) + lane];
      if (c & 1) {
        acc1.x += wc * r.x; acc1.y += wc * r.y;
        acc1.z += wc * r.z; acc1.w += wc * r.w;
      } else {
        acc0.x += wc * r.x; acc0.y += wc * r.y;
        acc0.z += wc * r.z; acc0.w += wc * r.w;
      }
    }
  }
  float4 o;
  o.x = (acc0.x + acc1.x) * inv;
  o.y = (acc0.y + acc1.y) * inv;
  o.z = (acc0.z + acc1.z) * inv;
  o.w = (acc0.w + acc1.w) * inv;
  *(float4*)(out + (size_t)pos * H + l4) = o;    // coalesced 1 KB per wave
}

extern "C" void kernel_launch(void* const* d_in, const int* in_sizes, int n_in,
                              void* d_out, int out_size, void* d_ws, size_t ws_size,
                              hipStream_t stream) {
  const int*   node_ids = (const int*)d_in[0];
  const int*   neighs   = (const int*)d_in[1];
  const int*   mask     = (const int*)d_in[2];
  const float* emb      = (const float*)d_in[3];
  const float* a_w      = (const float*)d_in[4];
  const float* a_b      = (const float*)d_in[5];
  float*       out      = (float*)d_out;

  const int npos = in_sizes[0];            // B*S = 4096
  const int V    = in_sizes[3] / H;        // 100001

  float2* pv = (float2*)d_ws;              // needs V*8 B = 800 KB of workspace

  proj_kernel<<<2048, 256, 0, stream>>>(emb, a_w, pv, V);
  agg_kernel<<<(npos + 3) / 4, 256, 0, stream>>>(node_ids, neighs, mask, emb,
                                                 pv, a_b, out, npos);
}

// Round 3
// 155.844 us; speedup vs baseline: 1.1317x; 1.1317x over previous
//
#include <hip/hip_runtime.h>
#include <math.h>

// GAT aggregation: B=8,S=512,N=32,H=256,V=100001  (npos = 4096)
// Round-13: revert the two-pass pv decomposition (R12 post-mortem: the row
// GATHER dominates at ~0.75 TB/s effective; proj only added a table stream,
// and the workspace use may also buy a timed 400 MB re-poison fill).
// Single kernel, ZERO workspace. Structure:
//  - 2 waves per position (block 256 = 4 waves = 2 positions).
//  - Each wave ballot-compacts survivors (redundant per wave, no barrier),
//    then issues ALL its row loads (self + every-2nd survivor, <=18 rows)
//    in one upfront burst -> ~150 KB outstanding per CU (1.8x R10's MLP).
//  - Rows live in VGPRs; used once for the dot partials and once for the
//    weighted FMA. Batched 18-value butterfly makes every dot total
//    available IN ALL LANES -> softmax weights are uniform VALU values,
//    no readlane chain, no per-weight broadcast.
//  - One __syncthreads; 2-way merge via LDS; even wave stores float4.
// Masked neighbors: weight exactly +0 (exp underflow), never loaded.

constexpr int   H     = 256;
constexpr int   NN    = 32;            // neighbors
constexpr int   C     = NN + 1;        // max candidates (self + neighbors)
constexpr int   JMAX  = (C + 1) / 2;   // max candidates per half-wave = 17
constexpr float SLOPE = 0.2f;

__global__ __launch_bounds__(256, 4) void gat_kernel(
    const int*   __restrict__ node_ids,  // [npos]
    const int*   __restrict__ neighs,    // [npos, NN]
    const int*   __restrict__ mask,      // [npos, NN]
    const float* __restrict__ emb,       // [V, H]
    const float* __restrict__ a_w,       // [2H]
    const float* __restrict__ a_b,       // [1]
    float*       __restrict__ out)       // [npos, H]
{
  __shared__ int    sidx[4][64];         // per-wave compacted survivor ids
  __shared__ float4 sacc[4][64];         // per-wave partial acc (1 KB each)
  __shared__ float  sm[4], ss[4];        // per-wave partial max / sum

  const int wv   = threadIdx.x >> 6;
  const int lane = threadIdx.x & 63;
  const int pos  = blockIdx.x * 2 + (wv >> 1);  // 2 positions per block
  const int half = wv & 1;                       // which half of survivors
  const int l4   = lane << 2;

  // ---- load indices/mask, ballot-compact (per wave, no barrier) ----
  bool active = false;
  int  my     = 0;
  if (lane == 0) {
    my = node_ids[pos];
    active = true;                                // self never masked
  } else if (lane <= NN) {
    my     = neighs[pos * NN + lane - 1];
    active = (mask[pos * NN + lane - 1] == 0);    // masked -> weight +0 -> skip
  }
  const unsigned long long bal = __ballot(active);
  const int K = (int)__popcll(bal);               // wave-uniform, K >= 1
  if (active)
    sidx[wv][(int)__popcll(bal & ((1ull << lane) - 1ull))] = my;
  // same-wave LDS write->read: DS ops are ordered within a wave
  const int cidx = sidx[wv][lane];                // lane k = survivor k's id

  const float4* __restrict__ embv = (const float4*)emb;
  const int iself = __builtin_amdgcn_readlane(cidx, 0);

  // ---- ALL row loads upfront: self + candidates {half, half+2, ...} ----
  const float4 rs = embv[(size_t)iself * (H / 4) + lane];  // self (zsrc dot)
  float4 buf[JMAX];
#pragma unroll
  for (int j = 0; j < JMAX; ++j) {
    const int c = half + 2 * j;
    if (c < K) {                                           // scalar guard
      const int ic = __builtin_amdgcn_readlane(cidx, c);   // SGPR row index
      buf[j] = embv[(size_t)ic * (H / 4) + lane];
    }
  }

  const float4 aw1 = *(const float4*)(a_w + l4);      // src half of a_w
  const float4 aw2 = *(const float4*)(a_w + H + l4);  // candidate half
  const float  ab  = a_b[0];

  // ---- per-lane dot partials, one batched butterfly over 18 values ----
  float red[JMAX + 1];
  red[0] = rs.x * aw1.x + rs.y * aw1.y + rs.z * aw1.z + rs.w * aw1.w;
#pragma unroll
  for (int j = 0; j < JMAX; ++j) {
    const int c = half + 2 * j;
    red[j + 1] = 0.f;
    if (c < K)
      red[j + 1] = buf[j].x * aw2.x + buf[j].y * aw2.y +
                   buf[j].z * aw2.z + buf[j].w * aw2.w;
  }
#pragma unroll
  for (int off = 32; off > 0; off >>= 1)
#pragma unroll
    for (int t = 0; t <= JMAX; ++t)
      red[t] += __shfl_xor(red[t], off, 64);
  const float zsrc = red[0];

  // ---- softmax over this half's logits: totals are IN EVERY LANE ----
  float m = -1e30f;
#pragma unroll
  for (int j = 0; j < JMAX; ++j) {
    const int c = half + 2 * j;
    if (c < K) {
      const float z = zsrc + red[j + 1] + ab;
      red[j + 1] = (z > 0.f) ? z : SLOPE * z;       // LeakyReLU(0.2), in place
      m = fmaxf(m, red[j + 1]);
    }
  }
  float  s   = 0.f;
  float4 acc = {0.f, 0.f, 0.f, 0.f};
#pragma unroll
  for (int j = 0; j < JMAX; ++j) {
    const int c = half + 2 * j;
    if (c < K) {
      const float pr = __expf(red[j + 1] - m);      // uniform across lanes
      s += pr;
      acc.x += pr * buf[j].x; acc.y += pr * buf[j].y;
      acc.z += pr * buf[j].z; acc.w += pr * buf[j].w;
    }
  }

  // ---- 2-way merge (single barrier; empty half: s=0, exp(-1e30-M)=+0) ----
  sacc[wv][lane] = acc;
  if (lane == 0) { sm[wv] = m; ss[wv] = s; }
  __syncthreads();

  if (half == 0) {
    const float  m1 = sm[wv + 1], s1 = ss[wv + 1];
    const float  M  = fmaxf(m, m1);
    const float  f0 = __expf(m - M);
    const float  f1 = __expf(m1 - M);
    const float4 a1 = sacc[wv + 1][lane];
    const float  inv = 1.f / (f0 * s + f1 * s1);
    float4 o;
    o.x = (f0 * acc.x + f1 * a1.x) * inv;
    o.y = (f0 * acc.y + f1 * a1.y) * inv;
    o.z = (f0 * acc.z + f1 * a1.z) * inv;
    o.w = (f0 * acc.w + f1 * a1.w) * inv;
    *(float4*)(out + (size_t)pos * H + l4) = o;     // coalesced 1 KB / wave
  }
}

extern "C" void kernel_launch(void* const* d_in, const int* in_sizes, int n_in,
                              void* d_out, int out_size, void* d_ws, size_t ws_size,
                              hipStream_t stream) {
  const int*   node_ids = (const int*)d_in[0];
  const int*   neighs   = (const int*)d_in[1];
  const int*   mask     = (const int*)d_in[2];
  const float* emb      = (const float*)d_in[3];
  const float* a_w      = (const float*)d_in[4];
  const float* a_b      = (const float*)d_in[5];
  float*       out      = (float*)d_out;

  const int npos = in_sizes[0];            // B*S = 4096 (even)
  gat_kernel<<<npos / 2, 256, 0, stream>>>(node_ids, neighs, mask, emb,
                                           a_w, a_b, out);
}

// Round 4
// 154.966 us; speedup vs baseline: 1.1381x; 1.0057x over previous
//
#include <hip/hip_runtime.h>
#include <math.h>

// GAT aggregation: B=8,S=512,N=32,H=256,V=100001  (npos = 4096)
// Round-14: discriminating experiment for the remaining-headroom question.
// Evidence so far: three different softmax/reduction structures (R10 serial,
// R12 scalar-gather, R13 wide-butterfly) all land within 4 us => the kernel
// is bound by the row-GATHER memory path, which is HBM-cold every iteration
// (the 400 MB workspace re-poison fill sweeps L3 before each timed launch).
// R13 (17-row bufs, ~140 VGPR, 3 waves/SIMD) was 3.8 us SLOWER than R10
// (9-row bufs, 5 waves/SIMD) despite fewer bytes => occupancy/latency
// exposure is the live variable.
// R14 = R10 geometry (WPB=4, <=9 rows/wave, one pos per block)
//       + R13's batched two-pass butterfly (proven equal-or-better)
//       + __launch_bounds__(256, 6): force 6 waves/SIMD (VGPR cap 85;
//         estimated need ~78) for maximum outstanding gather traffic.
// If this lands ~152 (no change): we are at the cold-gather floor + fixed
// harness overhead => roofline. If 140-148: latency exposure was real.

constexpr int   H     = 256;
constexpr int   NN    = 32;                  // neighbors
constexpr int   C     = NN + 1;              // max candidates (self + nbrs)
constexpr int   WPB   = 4;                   // waves per block (= per pos)
constexpr int   JMAX  = (C + WPB - 1) / WPB; // max candidates per wave = 9
constexpr int   NR    = JMAX + 1;            // batched reduction width = 10
constexpr float SLOPE = 0.2f;

__global__ __launch_bounds__(256, 6) void gat_kernel(
    const int*   __restrict__ node_ids,   // [npos]
    const int*   __restrict__ neighs,     // [npos, NN]
    const int*   __restrict__ mask,       // [npos, NN]
    const float* __restrict__ emb,        // [V, H]
    const float* __restrict__ a_w,        // [2H]
    const float* __restrict__ a_b,        // [1]
    float*       __restrict__ out)        // [npos, H]
{
  __shared__ int    sidx[WPB][64];        // per-wave compacted survivor ids
  __shared__ float  smx[WPB], ssum[WPB];  // per-wave partial m, s
  __shared__ float4 sacc[WPB][64];        // per-wave partial acc (1 KB each)

  const int pos  = blockIdx.x;
  const int wv   = threadIdx.x >> 6;
  const int lane = threadIdx.x & 63;
  const int l4   = lane << 2;

  // ---- every wave: load indices/mask, ballot-compact into own LDS slice ----
  bool active = false;
  int  my     = 0;
  if (lane == 0) {
    my = node_ids[pos];
    active = true;                               // self never masked
  } else if (lane <= NN) {
    my     = neighs[pos * NN + lane - 1];
    active = (mask[pos * NN + lane - 1] == 0);   // masked -> weight +0 -> skip
  }
  const unsigned long long bal = __ballot(active);
  const int K = (int)__popcll(bal);              // wave-uniform (SGPR)
  if (active)
    sidx[wv][(int)__popcll(bal & ((1ull << lane) - 1ull))] = my;
  // Same-wave LDS write->read: DS ops execute in order within a wave.
  const int cidx = sidx[wv][lane];               // lane k = survivor k's id
  const int swv  = __builtin_amdgcn_readfirstlane(wv);

  const float4* __restrict__ embv = (const float4*)emb; // row = H/4 float4

  // Self row (survivor 0): needed by every wave for zsrc (L1 broadcast).
  const int    iself = __builtin_amdgcn_readlane(cidx, 0);
  const float4 es    = embv[(size_t)iself * (H / 4) + lane];

  // This wave's candidate rows, all loaded upfront (independent, in flight).
  float4 buf[JMAX];
#pragma unroll
  for (int j = 0; j < JMAX; ++j) {
    const int c = swv + WPB * j;
    if (c < K) {                                          // scalar guard
      const int ic = __builtin_amdgcn_readlane(cidx, c);  // SGPR row index
      buf[j] = embv[(size_t)ic * (H / 4) + lane];
    }
  }

  const float4 aw1 = *(const float4*)(a_w + l4);        // src half of a_w
  const float4 aw2 = *(const float4*)(a_w + H + l4);    // candidate half
  const float  ab  = a_b[0];

  // Batched butterfly: zsrc + all candidate dots reduced together
  // (independent values -> DS ops pipeline instead of serializing).
  float red[NR];
  red[0] = es.x * aw1.x + es.y * aw1.y + es.z * aw1.z + es.w * aw1.w;
#pragma unroll
  for (int j = 0; j < JMAX; ++j) {
    const int c = swv + WPB * j;
    red[j + 1] = 0.f;
    if (c < K) {
      const float4 cur = buf[j];
      red[j + 1] = cur.x * aw2.x + cur.y * aw2.y +
                   cur.z * aw2.z + cur.w * aw2.w;
    }
  }
#pragma unroll
  for (int off = 32; off > 0; off >>= 1) {
#pragma unroll
    for (int t = 0; t < NR; ++t)
      red[t] += __shfl_xor(red[t], off, 64);
  }
  const float zsrc = red[0];

  // Two-pass softmax over this wave's (wave-uniform) logits.
  float m = -1e30f;
#pragma unroll
  for (int j = 0; j < JMAX; ++j) {
    const int c = swv + WPB * j;
    if (c < K) {
      const float z = zsrc + red[j + 1] + ab;
      red[j + 1] = (z > 0.f) ? z : SLOPE * z;    // LeakyReLU(0.2), in place
      m = fmaxf(m, red[j + 1]);
    }
  }
  float  s = 0.f;
  float4 acc = {0.f, 0.f, 0.f, 0.f};
#pragma unroll
  for (int j = 0; j < JMAX; ++j) {
    const int c = swv + WPB * j;
    if (c < K) {
      const float pr = __expf(red[j + 1] - m);   // uniform across lanes
      s += pr;
      const float4 cur = buf[j];
      acc.x += pr * cur.x;
      acc.y += pr * cur.y;
      acc.z += pr * cur.z;
      acc.w += pr * cur.w;
    }
  }

  // ---- block merge of the 4 partials (single barrier) ----
  sacc[wv][lane] = acc;
  if (lane == 0) { smx[wv] = m; ssum[wv] = s; }
  __syncthreads();

  if (wv == 0) {
    const float M = fmaxf(fmaxf(smx[0], smx[1]), fmaxf(smx[2], smx[3]));
    float  S = 0.f;
    float4 o = {0.f, 0.f, 0.f, 0.f};
#pragma unroll
    for (int w = 0; w < WPB; ++w) {
      const float f = __expf(smx[w] - M);  // empty wave: exp(-1e30-M) = +0
      S += ssum[w] * f;
      const float4 a = sacc[w][lane];
      o.x += f * a.x; o.y += f * a.y; o.z += f * a.z; o.w += f * a.w;
    }
    const float inv = 1.f / S;
    o.x *= inv; o.y *= inv; o.z *= inv; o.w *= inv;
    *(float4*)(out + (size_t)pos * H + l4) = o;  // coalesced 1 KB store
  }
}

extern "C" void kernel_launch(void* const* d_in, const int* in_sizes, int n_in,
                              void* d_out, int out_size, void* d_ws, size_t ws_size,
                              hipStream_t stream) {
  const int*   node_ids = (const int*)d_in[0];
  const int*   neighs   = (const int*)d_in[1];
  const int*   mask     = (const int*)d_in[2];
  const float* emb      = (const float*)d_in[3];
  const float* a_w      = (const float*)d_in[4];
  const float* a_b      = (const float*)d_in[5];
  float*       out      = (float*)d_out;

  const int npos = in_sizes[0];           // B*S = 4096
  gat_kernel<<<npos, 256, 0, stream>>>(node_ids, neighs, mask, emb, a_w, a_b,
                                       out);
}